// Round 16
// baseline (83.102 us; speedup 1.0000x reference)
//
#include <hip/hip_runtime.h>
#include <stdint.h>
#include <stddef.h>

typedef __bf16 bf16x8 __attribute__((ext_vector_type(8)));
typedef __bf16 bf16x4 __attribute__((ext_vector_type(4)));
typedef float  f32x4  __attribute__((ext_vector_type(4)));

#define MFMA16(A, B, C) __builtin_amdgcn_mfma_f32_16x16x32_bf16((A), (B), (C), 0, 0, 0)

// 0.125 (1/sqrt(64)) * log2(e), folded into Q at projection time.
#define QSCALE 0.18033688011112042f

// Raw v_exp_f32 (2^x); args bounded here so no range guards needed.
#if __has_builtin(__builtin_amdgcn_exp2f)
__device__ __forceinline__ float fast_exp2(float x) {
    return __builtin_amdgcn_exp2f(x);
}
#else
__device__ __forceinline__ float fast_exp2(float x) {
    float r;
    asm("v_exp_f32 %0, %1" : "=v"(r) : "v"(x));
    return r;
}
#endif

// Async global->LDS, 16B per lane. LDS dest is wave-uniform base + lane*16
// (HW rule); the per-lane GLOBAL address carries the swizzle permutation.
__device__ __forceinline__ void async_copy16(__bf16* lds, const __bf16* g) {
    __builtin_amdgcn_global_load_lds(
        (const __attribute__((address_space(1))) void*)g,
        (__attribute__((address_space(3))) void*)lds,
        16, 0, 0);
}

// ---------------------------------------------------------------------------
// Kernel 1: fused QKV projection (unchanged, proven r2-r15).
//   x [32768][768] fp32 -> Q (pre-scaled), K bf16 row-major [32768][64];
//   V transposed AND k-permuted per batch: within each 32-token chunk,
//   token (16*hi + 4*g + r) stored at (8*g + 4*hi + r).
// ---------------------------------------------------------------------------
__global__ __launch_bounds__(256) void qkv_proj_kernel(
    const float* __restrict__ x,
    const float* __restrict__ Wq, const float* __restrict__ bq,
    const float* __restrict__ Wk, const float* __restrict__ bk,
    const float* __restrict__ Wv, const float* __restrict__ bv,
    __bf16* __restrict__ Qg, __bf16* __restrict__ Kg, __bf16* __restrict__ Vpg)
{
    __shared__ __bf16 xs[64][40];
    __shared__ __bf16 wt[192][40];

    const int tid  = threadIdx.x;
    const int wid  = tid >> 6;
    const int lane = tid & 63;
    const int l15  = lane & 15;
    const int l4   = lane >> 4;
    const int m0   = blockIdx.x * 64;

    f32x4 acc[4][3];
    #pragma unroll
    for (int i = 0; i < 4; ++i)
        #pragma unroll
        for (int j = 0; j < 3; ++j)
            acc[i][j] = (f32x4){0.f, 0.f, 0.f, 0.f};

    for (int k0 = 0; k0 < 768; k0 += 32) {
        #pragma unroll
        for (int i = 0; i < 2; ++i) {
            int idx = tid + 256 * i;
            int row = idx >> 3;
            int c4  = idx & 7;
            const float4 v = *reinterpret_cast<const float4*>(
                x + (size_t)(m0 + row) * 768 + k0 + c4 * 4);
            bf16x4 t;
            t[0] = (__bf16)v.x; t[1] = (__bf16)v.y;
            t[2] = (__bf16)v.z; t[3] = (__bf16)v.w;
            *reinterpret_cast<bf16x4*>(&xs[row][c4 * 4]) = t;
        }
        #pragma unroll
        for (int i = 0; i < 6; ++i) {
            int idx = tid + 256 * i;
            int kg  = idx / 192;
            int c   = idx - kg * 192;
            const float* Wm = (c < 64) ? Wq : ((c < 128) ? Wk : Wv);
            int cc = c & 63;
            bf16x4 t;
            #pragma unroll
            for (int j = 0; j < 4; ++j)
                t[j] = (__bf16)Wm[(size_t)(k0 + kg * 4 + j) * 64 + cc];
            *reinterpret_cast<bf16x4*>(&wt[c][kg * 4]) = t;
        }
        __syncthreads();

        bf16x8 afrag[4];
        #pragma unroll
        for (int rf = 0; rf < 4; ++rf)
            afrag[rf] = *reinterpret_cast<const bf16x8*>(&xs[rf * 16 + l15][l4 * 8]);
        #pragma unroll
        for (int cf = 0; cf < 3; ++cf) {
            bf16x8 bfrag = *reinterpret_cast<const bf16x8*>(
                &wt[wid * 48 + cf * 16 + l15][l4 * 8]);
            #pragma unroll
            for (int rf = 0; rf < 4; ++rf)
                acc[rf][cf] = MFMA16(afrag[rf], bfrag, acc[rf][cf]);
        }
        __syncthreads();
    }

    #pragma unroll
    for (int cf = 0; cf < 3; ++cf) {
        int col = wid * 48 + cf * 16 + l15;
        int mi  = col >> 6;                   // 0=Q 1=K 2=V
        int h   = col & 63;
        float bias = (mi == 0) ? bq[h] : ((mi == 1) ? bk[h] : bv[h]);
        float scl  = (mi == 0) ? QSCALE : 1.0f;
        #pragma unroll
        for (int rf = 0; rf < 4; ++rf) {
            int r0 = rf * 16 + l4 * 4;
            if (mi == 2) {
                int m  = m0 + r0;
                int bb = m >> 12;
                int n0 = m & 4095;
                int n0p = (n0 & ~31) | (l4 * 8 + (rf & 1) * 4);
                bf16x4 t;
                #pragma unroll
                for (int r = 0; r < 4; ++r)
                    t[r] = (__bf16)(acc[rf][cf][r] + bias);
                *reinterpret_cast<bf16x4*>(
                    Vpg + ((size_t)bb * 64 + h) * 4096 + n0p) = t;
            } else {
                __bf16* G = (mi == 0) ? Qg : Kg;
                #pragma unroll
                for (int r = 0; r < 4; ++r)
                    G[(size_t)(m0 + r0 + r) * 64 + h] =
                        (__bf16)((acc[rf][cf][r] + bias) * scl);
            }
        }
    }
}

// ---------------------------------------------------------------------------
// Kernel 2: flash attention, 64-q-per-wave variant. Block = 8 waves = one
// 64-q tile x 4096 keys; wave ks (=wid) is a key STREAM: 512 keys (16
// chunks) against ALL 64 q (4 sets of 16). Each LDS K/V fragment read now
// feeds 4 MFMAs (was 2) -> LDS read traffic halves; MFMA/DMA/exp2 totals
// conserved. r9-verbatim per-iter mechanics: K+V DMA->LDS double-buffered
// (8 streams x 2 bufs = 128 KB), XOR swizzle via pre-swizzled global
// source, __syncthreads/iter with issue-at-top order, no max tracking,
// raw v_exp_f32. Epilogue: 8-stream binary-tree merge in LDS (plain sums,
// exact), single normalize+store by stream 0. launch_bounds(512,2) allows
// up to 256 VGPR -> no spill at ~190; 2 waves/SIMD (MFMA-dense regime).
// ---------------------------------------------------------------------------
__global__ __launch_bounds__(512, 2) void attn_kernel(
    const __bf16* __restrict__ Qg, const __bf16* __restrict__ Kg,
    const __bf16* __restrict__ Vpg, float* __restrict__ out)
{
    // arena: K 8 streams * 2 bufs * 32*64 = 32768 elems (64 KB)
    //        V 8 streams * 2 bufs * 64*32 = 32768 elems (64 KB) -> 128 KB
    // overlay (after loop): lbuf 8*64 f32 (2 KB) + obuf 4*[64][68] (69.6 KB)
    __shared__ __align__(16) char smem[131072];
    __bf16* ksbase = reinterpret_cast<__bf16*>(smem);
    __bf16* vsbase = ksbase + 8 * 2 * 32 * 64;

    const int tid  = threadIdx.x;
    const int wid  = tid >> 6;
    const int lane = tid & 63;
    const int l15  = lane & 15;
    const int l4   = lane >> 4;
    const int ks   = wid;              // key stream 0..7
    const int b    = blockIdx.x & 7;   // batch -> XCD
    const int qt   = blockIdx.x >> 3;  // 0..63
    const int q0   = qt * 64;

    const __bf16* Kb = Kg  + (size_t)b * 4096 * 64;
    const __bf16* Vb = Vpg + (size_t)b * 64 * 4096;

    __bf16* kst0 = ksbase + (ks * 2 + 0) * 32 * 64;
    __bf16* kst1 = ksbase + (ks * 2 + 1) * 32 * 64;
    __bf16* vst0 = vsbase + (ks * 2 + 0) * 64 * 32;
    __bf16* vst1 = vsbase + (ks * 2 + 1) * 64 * 32;

    // loop-invariant swizzled LDS element offsets (read side, r9-proven)
    int koff[2][2], voff[4];
    #pragma unroll
    for (int dc = 0; dc < 2; ++dc)
        #pragma unroll
        for (int cf = 0; cf < 2; ++cf) {
            int row = cf * 16 + l15;
            koff[dc][cf] = row * 64 + (((dc * 4 + l4) ^ (row & 7)) * 8);
        }
    #pragma unroll
    for (int ht = 0; ht < 4; ++ht) {
        int row = ht * 16 + l15;
        voff[ht] = row * 32 + ((l4 ^ (row & 3)) * 8);
    }

    // staging source addressing (pre-swizzled global granules, r9-proven;
    // full tile per wave now: 4 K-DMAs cover rows j*8.., 4 V-DMAs j*16..)
    const int krow = lane >> 3;                      // 0..7
    const int kg_s = (lane & 7) ^ (lane >> 3);
    const int vrow = lane >> 2;                      // 0..15
    const int vg_s = (lane & 3) ^ ((lane >> 2) & 3);

    auto issue_stage = [&](__bf16* kp, __bf16* vp, int c) {
        #pragma unroll
        for (int j = 0; j < 4; ++j) {
            async_copy16(kp + j * 8 * 64,
                         Kb + (size_t)(c * 32 + j * 8 + krow) * 64 + kg_s * 8);
            async_copy16(vp + j * 16 * 32,
                         Vb + (size_t)(j * 16 + vrow) * 4096 + c * 32 + vg_s * 8);
        }
    };

    // Q B-frags for the four 16-row sets (pre-scaled by QSCALE)
    bf16x8 aq[4][2];
    #pragma unroll
    for (int set = 0; set < 4; ++set)
        #pragma unroll
        for (int dc = 0; dc < 2; ++dc)
            aq[set][dc] = *reinterpret_cast<const bf16x8*>(
                Qg + (size_t)(b * 4096 + q0 + set * 16 + l15) * 64 + dc * 32 + l4 * 8);

    f32x4 lacc[4];
    f32x4 o[4][4];
    #pragma unroll
    for (int set = 0; set < 4; ++set) {
        lacc[set] = (f32x4){0.f, 0.f, 0.f, 0.f};
        #pragma unroll
        for (int ht = 0; ht < 4; ++ht)
            o[set][ht] = (f32x4){0.f, 0.f, 0.f, 0.f};
    }

    const int c0 = ks * 16;            // this stream's first 32-key chunk
    issue_stage(kst0, vst0, c0);

    for (int t = 0; t < 16; ++t) {
        __syncthreads();               // drains own async loads -> cur buf ready
        const __bf16* kp = (t & 1) ? kst1 : kst0;
        const __bf16* vp = (t & 1) ? vst1 : vst0;
        __bf16* kpn = (t & 1) ? kst0 : kst1;
        __bf16* vpn = (t & 1) ? vst0 : vst1;
        const bool pre = (t + 1) < 16;
        if (pre) issue_stage(kpn, vpn, c0 + t + 1);

        // S^T = K * Q^T : s[set][cf] reg r = S[q=l15][key = cf*16 + 4*l4 + r]
        f32x4 s[4][2];
        #pragma unroll
        for (int set = 0; set < 4; ++set)
            #pragma unroll
            for (int cf = 0; cf < 2; ++cf)
                s[set][cf] = (f32x4){0.f, 0.f, 0.f, 0.f};
        __builtin_amdgcn_s_setprio(1);
        #pragma unroll
        for (int dc = 0; dc < 2; ++dc)
            #pragma unroll
            for (int cf = 0; cf < 2; ++cf) {
                bf16x8 kf = *reinterpret_cast<const bf16x8*>(kp + koff[dc][cf]);
                #pragma unroll
                for (int set = 0; set < 4; ++set)
                    s[set][cf] = MFMA16(kf, aq[set][dc], s[set][cf]);
            }
        __builtin_amdgcn_s_setprio(0);

        // p = 2^s (raw v_exp_f32); accumulate l as vectors
        #pragma unroll
        for (int set = 0; set < 4; ++set) {
            #pragma unroll
            for (int cf = 0; cf < 2; ++cf)
                #pragma unroll
                for (int r = 0; r < 4; ++r)
                    s[set][cf][r] = fast_exp2(s[set][cf][r]);
            lacc[set] += s[set][0];
            lacc[set] += s[set][1];
        }

        // P^T B-frags (in-lane repack, sigma-permuted key order)
        bf16x8 pb[4];
        #pragma unroll
        for (int set = 0; set < 4; ++set)
            #pragma unroll
            for (int j = 0; j < 4; ++j) {
                pb[set][j]     = (__bf16)s[set][0][j];
                pb[set][j + 4] = (__bf16)s[set][1][j];
            }

        // O^T += V^T * P^T (each vf feeds 4 sets)
        __builtin_amdgcn_s_setprio(1);
        #pragma unroll
        for (int ht = 0; ht < 4; ++ht) {
            bf16x8 vf = *reinterpret_cast<const bf16x8*>(vp + voff[ht]);
            #pragma unroll
            for (int set = 0; set < 4; ++set)
                o[set][ht] = MFMA16(vf, pb[set], o[set][ht]);
        }
        __builtin_amdgcn_s_setprio(0);
    }

    // per-stream l partials (q = set*16 + l15)
    float lw[4];
    #pragma unroll
    for (int set = 0; set < 4; ++set) {
        float v = lacc[set][0] + lacc[set][1] + lacc[set][2] + lacc[set][3];
        v += __shfl_xor(v, 16);
        v += __shfl_xor(v, 32);
        lw[set] = v;
    }

    // ---- 8-stream binary-tree merge via LDS overlay (plain sums, exact) ----
    __syncthreads();                    // all streams done with arena
    float* lbuf = reinterpret_cast<float*>(smem);   // [8 ks][64 q]
    float* obuf = lbuf + 512;                        // 4 x [64 q][68]
    const int hcol = 4 * l4;

    if (l4 == 0) {
        #pragma unroll
        for (int set = 0; set < 4; ++set)
            lbuf[ks * 64 + set * 16 + l15] = lw[set];
    }

    auto writeO = [&](int bufi) {
        #pragma unroll
        for (int set = 0; set < 4; ++set)
            #pragma unroll
            for (int ht = 0; ht < 4; ++ht)
                *reinterpret_cast<f32x4*>(
                    &obuf[bufi * 4352 + (set * 16 + l15) * 68 + ht * 16 + hcol]) =
                    o[set][ht];
    };
    auto addO = [&](int bufi) {
        #pragma unroll
        for (int set = 0; set < 4; ++set)
            #pragma unroll
            for (int ht = 0; ht < 4; ++ht) {
                f32x4 p = *reinterpret_cast<const f32x4*>(
                    &obuf[bufi * 4352 + (set * 16 + l15) * 68 + ht * 16 + hcol]);
                o[set][ht][0] += p[0]; o[set][ht][1] += p[1];
                o[set][ht][2] += p[2]; o[set][ht][3] += p[3];
            }
    };

    if (ks >= 4) writeO(ks - 4);
    __syncthreads();
    if (ks < 4) addO(ks);
    __syncthreads();
    if (ks == 2 || ks == 3) writeO(ks - 2);
    __syncthreads();
    if (ks < 2) addO(ks);
    __syncthreads();
    if (ks == 1) writeO(0);
    __syncthreads();
    if (ks == 0) {
        addO(0);
        #pragma unroll
        for (int set = 0; set < 4; ++set) {
            int q = set * 16 + l15;
            float L = 0.f;
            #pragma unroll
            for (int k = 0; k < 8; ++k)
                L += lbuf[k * 64 + q];
            float inv = 1.0f / L;
            #pragma unroll
            for (int ht = 0; ht < 4; ++ht) {
                f32x4 acc = o[set][ht];
                acc[0] *= inv; acc[1] *= inv; acc[2] *= inv; acc[3] *= inv;
                *reinterpret_cast<f32x4*>(
                    out + (size_t)(b * 4096 + q0 + q) * 64 + ht * 16 + hcol) = acc;
            }
        }
    }
}

extern "C" void kernel_launch(void* const* d_in, const int* in_sizes, int n_in,
                              void* d_out, int out_size, void* d_ws, size_t ws_size,
                              hipStream_t stream)
{
    (void)in_sizes; (void)n_in; (void)out_size; (void)ws_size;
    const float* x  = (const float*)d_in[0];
    const float* Wq = (const float*)d_in[1];
    const float* bq = (const float*)d_in[2];
    const float* Wk = (const float*)d_in[3];
    const float* bk = (const float*)d_in[4];
    const float* Wv = (const float*)d_in[5];
    const float* bv = (const float*)d_in[6];
    float* out = (float*)d_out;

    __bf16* Qg  = (__bf16*)d_ws;                    // [32768][64] bf16 (scaled)
    __bf16* Kg  = Qg + (size_t)32768 * 64;          // [32768][64] bf16
    __bf16* Vpg = Kg + (size_t)32768 * 64;          // [8][64][4096] bf16 permuted

    qkv_proj_kernel<<<512, 256, 0, stream>>>(x, Wq, bq, Wk, bk, Wv, bv, Qg, Kg, Vpg);
    attn_kernel<<<512, 512, 0, stream>>>(Qg, Kg, Vpg, out);
}

// Round 17
// 73.764 us; speedup vs baseline: 1.1266x; 1.1266x over previous
//
#include <hip/hip_runtime.h>
#include <stdint.h>
#include <stddef.h>

typedef __bf16 bf16x8 __attribute__((ext_vector_type(8)));
typedef __bf16 bf16x4 __attribute__((ext_vector_type(4)));
typedef float  f32x4  __attribute__((ext_vector_type(4)));

#define MFMA16(A, B, C) __builtin_amdgcn_mfma_f32_16x16x32_bf16((A), (B), (C), 0, 0, 0)

// 0.125 (1/sqrt(64)) * log2(e), folded into Q at projection time.
#define QSCALE 0.18033688011112042f

// Raw v_exp_f32 (2^x); args bounded here so no range guards needed.
#if __has_builtin(__builtin_amdgcn_exp2f)
__device__ __forceinline__ float fast_exp2(float x) {
    return __builtin_amdgcn_exp2f(x);
}
#else
__device__ __forceinline__ float fast_exp2(float x) {
    float r;
    asm("v_exp_f32 %0, %1" : "=v"(r) : "v"(x));
    return r;
}
#endif

// Async global->LDS, 16B per lane. LDS dest is wave-uniform base + lane*16
// (HW rule); the per-lane GLOBAL address carries the swizzle permutation.
__device__ __forceinline__ void async_copy16(__bf16* lds, const __bf16* g) {
    __builtin_amdgcn_global_load_lds(
        (const __attribute__((address_space(1))) void*)g,
        (__attribute__((address_space(3))) void*)lds,
        16, 0, 0);
}

// ---------------------------------------------------------------------------
// Kernel 1: fused QKV projection (unchanged, proven r2-r16).
//   x [32768][768] fp32 -> Q (pre-scaled), K bf16 row-major [32768][64];
//   V transposed AND k-permuted per batch: within each 32-token chunk,
//   token (16*hi + 4*g + r) stored at (8*g + 4*hi + r).
// ---------------------------------------------------------------------------
__global__ __launch_bounds__(256) void qkv_proj_kernel(
    const float* __restrict__ x,
    const float* __restrict__ Wq, const float* __restrict__ bq,
    const float* __restrict__ Wk, const float* __restrict__ bk,
    const float* __restrict__ Wv, const float* __restrict__ bv,
    __bf16* __restrict__ Qg, __bf16* __restrict__ Kg, __bf16* __restrict__ Vpg)
{
    __shared__ __bf16 xs[64][40];
    __shared__ __bf16 wt[192][40];

    const int tid  = threadIdx.x;
    const int wid  = tid >> 6;
    const int lane = tid & 63;
    const int l15  = lane & 15;
    const int l4   = lane >> 4;
    const int m0   = blockIdx.x * 64;

    f32x4 acc[4][3];
    #pragma unroll
    for (int i = 0; i < 4; ++i)
        #pragma unroll
        for (int j = 0; j < 3; ++j)
            acc[i][j] = (f32x4){0.f, 0.f, 0.f, 0.f};

    for (int k0 = 0; k0 < 768; k0 += 32) {
        #pragma unroll
        for (int i = 0; i < 2; ++i) {
            int idx = tid + 256 * i;
            int row = idx >> 3;
            int c4  = idx & 7;
            const float4 v = *reinterpret_cast<const float4*>(
                x + (size_t)(m0 + row) * 768 + k0 + c4 * 4);
            bf16x4 t;
            t[0] = (__bf16)v.x; t[1] = (__bf16)v.y;
            t[2] = (__bf16)v.z; t[3] = (__bf16)v.w;
            *reinterpret_cast<bf16x4*>(&xs[row][c4 * 4]) = t;
        }
        #pragma unroll
        for (int i = 0; i < 6; ++i) {
            int idx = tid + 256 * i;
            int kg  = idx / 192;
            int c   = idx - kg * 192;
            const float* Wm = (c < 64) ? Wq : ((c < 128) ? Wk : Wv);
            int cc = c & 63;
            bf16x4 t;
            #pragma unroll
            for (int j = 0; j < 4; ++j)
                t[j] = (__bf16)Wm[(size_t)(k0 + kg * 4 + j) * 64 + cc];
            *reinterpret_cast<bf16x4*>(&wt[c][kg * 4]) = t;
        }
        __syncthreads();

        bf16x8 afrag[4];
        #pragma unroll
        for (int rf = 0; rf < 4; ++rf)
            afrag[rf] = *reinterpret_cast<const bf16x8*>(&xs[rf * 16 + l15][l4 * 8]);
        #pragma unroll
        for (int cf = 0; cf < 3; ++cf) {
            bf16x8 bfrag = *reinterpret_cast<const bf16x8*>(
                &wt[wid * 48 + cf * 16 + l15][l4 * 8]);
            #pragma unroll
            for (int rf = 0; rf < 4; ++rf)
                acc[rf][cf] = MFMA16(afrag[rf], bfrag, acc[rf][cf]);
        }
        __syncthreads();
    }

    #pragma unroll
    for (int cf = 0; cf < 3; ++cf) {
        int col = wid * 48 + cf * 16 + l15;
        int mi  = col >> 6;                   // 0=Q 1=K 2=V
        int h   = col & 63;
        float bias = (mi == 0) ? bq[h] : ((mi == 1) ? bk[h] : bv[h]);
        float scl  = (mi == 0) ? QSCALE : 1.0f;
        #pragma unroll
        for (int rf = 0; rf < 4; ++rf) {
            int r0 = rf * 16 + l4 * 4;
            if (mi == 2) {
                int m  = m0 + r0;
                int bb = m >> 12;
                int n0 = m & 4095;
                int n0p = (n0 & ~31) | (l4 * 8 + (rf & 1) * 4);
                bf16x4 t;
                #pragma unroll
                for (int r = 0; r < 4; ++r)
                    t[r] = (__bf16)(acc[rf][cf][r] + bias);
                *reinterpret_cast<bf16x4*>(
                    Vpg + ((size_t)bb * 64 + h) * 4096 + n0p) = t;
            } else {
                __bf16* G = (mi == 0) ? Qg : Kg;
                #pragma unroll
                for (int r = 0; r < 4; ++r)
                    G[(size_t)(m0 + r0 + r) * 64 + h] =
                        (__bf16)((acc[rf][cf][r] + bias) * scl);
            }
        }
    }
}

// ---------------------------------------------------------------------------
// Kernel 2: flash attention, BARRIER-FREE main loop via wave-private staging.
// Block = 4 waves (256 thr) = one 64-q tile x 4096 keys; wave ks owns a
// PRIVATE 1024-key stream and PRIVATE double-buffered K[32][64]/V[64][32]
// LDS tiles (16 KB/wave, 64 KB/block -> 2 blocks/CU). No cross-wave data
// flow in the loop -> no __syncthreads: per-iter self-sync is one explicit
// s_waitcnt vmcnt(0) (drains own tile-t DMAs, issued a full iteration ago).
// Body order: vmcnt(0)+sched_barrier -> ds_read all frags -> issue t+1 DMAs
// (fly during compute) -> QK MFMA -> exp2 -> PV MFMA. Decoupled waves stall
// at different times -> mutual latency hiding (the thing lockstep forbade).
// Each LDS fragment read feeds 4 MFMAs (64 q per wave, r16's reuse).
// No max tracking (bounded scores), raw v_exp_f32, sigma-permuted PV.
// Epilogue: r14-style sequential-overlay merge of the 4 key streams
// (plain sums, exact), barriers in epilogue only.
// ---------------------------------------------------------------------------
__global__ __launch_bounds__(256, 2) void attn_kernel(
    const __bf16* __restrict__ Qg, const __bf16* __restrict__ Kg,
    const __bf16* __restrict__ Vpg, float* __restrict__ out)
{
    // arena: K 4 waves * 2 bufs * 32*64 = 16384 elems (32 KB)
    //        V 4 waves * 2 bufs * 64*32 = 16384 elems (32 KB) -> 64 KB
    // epilogue overlay: lbuf 4*64 f32 (1 KB) + obuf [64][68] f32 (17.4 KB)
    __shared__ __align__(16) char smem[65536];
    __bf16* ksbase = reinterpret_cast<__bf16*>(smem);
    __bf16* vsbase = ksbase + 4 * 2 * 32 * 64;

    const int tid  = threadIdx.x;
    const int wid  = tid >> 6;
    const int lane = tid & 63;
    const int l15  = lane & 15;
    const int l4   = lane >> 4;
    const int ks   = wid;              // private key stream 0..3
    const int b    = blockIdx.x & 7;   // batch -> XCD
    const int qt   = blockIdx.x >> 3;  // 0..63
    const int q0   = qt * 64;

    const __bf16* Kb = Kg  + (size_t)b * 4096 * 64;
    const __bf16* Vb = Vpg + (size_t)b * 64 * 4096;

    __bf16* kst0 = ksbase + (ks * 2 + 0) * 32 * 64;
    __bf16* kst1 = ksbase + (ks * 2 + 1) * 32 * 64;
    __bf16* vst0 = vsbase + (ks * 2 + 0) * 64 * 32;
    __bf16* vst1 = vsbase + (ks * 2 + 1) * 64 * 32;

    // loop-invariant swizzled LDS element offsets (read side, r9-proven)
    int koff[2][2], voff[4];
    #pragma unroll
    for (int dc = 0; dc < 2; ++dc)
        #pragma unroll
        for (int cf = 0; cf < 2; ++cf) {
            int row = cf * 16 + l15;
            koff[dc][cf] = row * 64 + (((dc * 4 + l4) ^ (row & 7)) * 8);
        }
    #pragma unroll
    for (int ht = 0; ht < 4; ++ht) {
        int row = ht * 16 + l15;
        voff[ht] = row * 32 + ((l4 ^ (row & 3)) * 8);
    }

    // staging source addressing (pre-swizzled global granules, r16-proven:
    // full tile per wave, 4 K-DMAs rows j*8.., 4 V-DMAs rows j*16..)
    const int krow = lane >> 3;                      // 0..7
    const int kg_s = (lane & 7) ^ (lane >> 3);
    const int vrow = lane >> 2;                      // 0..15
    const int vg_s = (lane & 3) ^ ((lane >> 2) & 3);

    auto issue_stage = [&](__bf16* kp, __bf16* vp, int c) {
        #pragma unroll
        for (int j = 0; j < 4; ++j) {
            async_copy16(kp + j * 8 * 64,
                         Kb + (size_t)(c * 32 + j * 8 + krow) * 64 + kg_s * 8);
            async_copy16(vp + j * 16 * 32,
                         Vb + (size_t)(j * 16 + vrow) * 4096 + c * 32 + vg_s * 8);
        }
    };

    // Q B-frags for the four 16-row sets (pre-scaled by QSCALE)
    bf16x8 aq[4][2];
    #pragma unroll
    for (int set = 0; set < 4; ++set)
        #pragma unroll
        for (int dc = 0; dc < 2; ++dc)
            aq[set][dc] = *reinterpret_cast<const bf16x8*>(
                Qg + (size_t)(b * 4096 + q0 + set * 16 + l15) * 64 + dc * 32 + l4 * 8);

    f32x4 lacc[4];
    f32x4 o[4][4];
    #pragma unroll
    for (int set = 0; set < 4; ++set) {
        lacc[set] = (f32x4){0.f, 0.f, 0.f, 0.f};
        #pragma unroll
        for (int ht = 0; ht < 4; ++ht)
            o[set][ht] = (f32x4){0.f, 0.f, 0.f, 0.f};
    }

    const int c0 = ks * 32;            // this wave's first 32-key chunk
    issue_stage(kst0, vst0, c0);

    for (int t = 0; t < 32; ++t) {
        // self-sync: drain own DMAs for tile t (issued one iteration ago;
        // t+1 DMAs are issued AFTER the reads below, so never drained here)
        asm volatile("s_waitcnt vmcnt(0)" ::: "memory");
        __builtin_amdgcn_sched_barrier(0);

        const __bf16* kp = (t & 1) ? kst1 : kst0;
        const __bf16* vp = (t & 1) ? vst1 : vst0;
        __bf16* kpn = (t & 1) ? kst0 : kst1;
        __bf16* vpn = (t & 1) ? vst0 : vst1;
        const bool pre = (t + 1) < 32;

        // ds_read ALL fragments of tile t (wave-private buffer)
        bf16x8 kfr[2][2], vfr[4];
        #pragma unroll
        for (int dc = 0; dc < 2; ++dc)
            #pragma unroll
            for (int cf = 0; cf < 2; ++cf)
                kfr[dc][cf] = *reinterpret_cast<const bf16x8*>(kp + koff[dc][cf]);
        #pragma unroll
        for (int ht = 0; ht < 4; ++ht)
            vfr[ht] = *reinterpret_cast<const bf16x8*>(vp + voff[ht]);

        // issue next tile's DMAs into the other private buffer
        if (pre) issue_stage(kpn, vpn, c0 + t + 1);

        // S^T = K * Q^T : s[set][cf] reg r = S[q=l15][key = cf*16 + 4*l4 + r]
        f32x4 s[4][2];
        #pragma unroll
        for (int set = 0; set < 4; ++set)
            #pragma unroll
            for (int cf = 0; cf < 2; ++cf)
                s[set][cf] = (f32x4){0.f, 0.f, 0.f, 0.f};
        __builtin_amdgcn_s_setprio(1);
        #pragma unroll
        for (int dc = 0; dc < 2; ++dc)
            #pragma unroll
            for (int cf = 0; cf < 2; ++cf)
                #pragma unroll
                for (int set = 0; set < 4; ++set)
                    s[set][cf] = MFMA16(kfr[dc][cf], aq[set][dc], s[set][cf]);
        __builtin_amdgcn_s_setprio(0);

        // p = 2^s (raw v_exp_f32); accumulate l as vectors
        #pragma unroll
        for (int set = 0; set < 4; ++set) {
            #pragma unroll
            for (int cf = 0; cf < 2; ++cf)
                #pragma unroll
                for (int r = 0; r < 4; ++r)
                    s[set][cf][r] = fast_exp2(s[set][cf][r]);
            lacc[set] += s[set][0];
            lacc[set] += s[set][1];
        }

        // P^T B-frags (in-lane repack, sigma-permuted key order)
        bf16x8 pb[4];
        #pragma unroll
        for (int set = 0; set < 4; ++set)
            #pragma unroll
            for (int j = 0; j < 4; ++j) {
                pb[set][j]     = (__bf16)s[set][0][j];
                pb[set][j + 4] = (__bf16)s[set][1][j];
            }

        // O^T += V^T * P^T (each vf feeds 4 sets)
        __builtin_amdgcn_s_setprio(1);
        #pragma unroll
        for (int ht = 0; ht < 4; ++ht)
            #pragma unroll
            for (int set = 0; set < 4; ++set)
                o[set][ht] = MFMA16(vfr[ht], pb[set], o[set][ht]);
        __builtin_amdgcn_s_setprio(0);
    }

    // per-wave l partials (q = set*16 + l15)
    float lw[4];
    #pragma unroll
    for (int set = 0; set < 4; ++set) {
        float v = lacc[set][0] + lacc[set][1] + lacc[set][2] + lacc[set][3];
        v += __shfl_xor(v, 16);
        v += __shfl_xor(v, 32);
        lw[set] = v;
    }

    // ---- sequential-overlay merge of the 4 private streams (plain sums) ----
    __syncthreads();                    // all waves done with the arena
    float* lbuf = reinterpret_cast<float*>(smem);   // [4 ks][64 q]
    float* obuf = lbuf + 256;                       // [64 q][68]
    const int hcol = 4 * l4;

    if (l4 == 0) {
        #pragma unroll
        for (int set = 0; set < 4; ++set)
            lbuf[ks * 64 + set * 16 + l15] = lw[set];
    }
    #pragma unroll
    for (int k = 1; k < 4; ++k) {
        if (ks == k) {
            #pragma unroll
            for (int set = 0; set < 4; ++set)
                #pragma unroll
                for (int ht = 0; ht < 4; ++ht)
                    *reinterpret_cast<f32x4*>(
                        &obuf[(set * 16 + l15) * 68 + ht * 16 + hcol]) = o[set][ht];
        }
        __syncthreads();
        if (ks == 0) {
            #pragma unroll
            for (int set = 0; set < 4; ++set)
                #pragma unroll
                for (int ht = 0; ht < 4; ++ht) {
                    f32x4 p = *reinterpret_cast<const f32x4*>(
                        &obuf[(set * 16 + l15) * 68 + ht * 16 + hcol]);
                    o[set][ht][0] += p[0]; o[set][ht][1] += p[1];
                    o[set][ht][2] += p[2]; o[set][ht][3] += p[3];
                }
        }
        __syncthreads();
    }

    if (ks == 0) {
        #pragma unroll
        for (int set = 0; set < 4; ++set) {
            int q = set * 16 + l15;
            float L = lbuf[q] + lbuf[64 + q] + lbuf[128 + q] + lbuf[192 + q];
            float inv = 1.0f / L;
            #pragma unroll
            for (int ht = 0; ht < 4; ++ht) {
                f32x4 acc = o[set][ht];
                acc[0] *= inv; acc[1] *= inv; acc[2] *= inv; acc[3] *= inv;
                *reinterpret_cast<f32x4*>(
                    out + (size_t)(b * 4096 + q0 + q) * 64 + ht * 16 + hcol) = acc;
            }
        }
    }
}

extern "C" void kernel_launch(void* const* d_in, const int* in_sizes, int n_in,
                              void* d_out, int out_size, void* d_ws, size_t ws_size,
                              hipStream_t stream)
{
    (void)in_sizes; (void)n_in; (void)out_size; (void)ws_size;
    const float* x  = (const float*)d_in[0];
    const float* Wq = (const float*)d_in[1];
    const float* bq = (const float*)d_in[2];
    const float* Wk = (const float*)d_in[3];
    const float* bk = (const float*)d_in[4];
    const float* Wv = (const float*)d_in[5];
    const float* bv = (const float*)d_in[6];
    float* out = (float*)d_out;

    __bf16* Qg  = (__bf16*)d_ws;                    // [32768][64] bf16 (scaled)
    __bf16* Kg  = Qg + (size_t)32768 * 64;          // [32768][64] bf16
    __bf16* Vpg = Kg + (size_t)32768 * 64;          // [8][64][4096] bf16 permuted

    qkv_proj_kernel<<<512, 256, 0, stream>>>(x, Wq, bq, Wk, bk, Wv, bv, Qg, Kg, Vpg);
    attn_kernel<<<512, 256, 0, stream>>>(Qg, Kg, Vpg, out);
}

// Round 18
// 73.012 us; speedup vs baseline: 1.1382x; 1.0103x over previous
//
#include <hip/hip_runtime.h>
#include <stdint.h>
#include <stddef.h>

typedef __bf16 bf16x8 __attribute__((ext_vector_type(8)));
typedef __bf16 bf16x4 __attribute__((ext_vector_type(4)));
typedef float  f32x4  __attribute__((ext_vector_type(4)));

#define MFMA16(A, B, C) __builtin_amdgcn_mfma_f32_16x16x32_bf16((A), (B), (C), 0, 0, 0)

// 0.125 (1/sqrt(64)) * log2(e), folded into Q at projection time.
#define QSCALE 0.18033688011112042f

// Raw v_exp_f32 (2^x); args bounded here so no range guards needed.
#if __has_builtin(__builtin_amdgcn_exp2f)
__device__ __forceinline__ float fast_exp2(float x) {
    return __builtin_amdgcn_exp2f(x);
}
#else
__device__ __forceinline__ float fast_exp2(float x) {
    float r;
    asm("v_exp_f32 %0, %1" : "=v"(r) : "v"(x));
    return r;
}
#endif

// Async global->LDS, 16B per lane. LDS dest is wave-uniform base + lane*16
// (HW rule); the per-lane GLOBAL address carries the swizzle permutation.
__device__ __forceinline__ void async_copy16(__bf16* lds, const __bf16* g) {
    __builtin_amdgcn_global_load_lds(
        (const __attribute__((address_space(1))) void*)g,
        (__attribute__((address_space(3))) void*)lds,
        16, 0, 0);
}

// ---------------------------------------------------------------------------
// Kernel 1: fused QKV projection (unchanged, proven r2-r17).
//   x [32768][768] fp32 -> Q (pre-scaled), K bf16 row-major [32768][64];
//   V transposed AND k-permuted per batch: within each 32-token chunk,
//   token (16*hi + 4*g + r) stored at (8*g + 4*hi + r).
// ---------------------------------------------------------------------------
__global__ __launch_bounds__(256) void qkv_proj_kernel(
    const float* __restrict__ x,
    const float* __restrict__ Wq, const float* __restrict__ bq,
    const float* __restrict__ Wk, const float* __restrict__ bk,
    const float* __restrict__ Wv, const float* __restrict__ bv,
    __bf16* __restrict__ Qg, __bf16* __restrict__ Kg, __bf16* __restrict__ Vpg)
{
    __shared__ __bf16 xs[64][40];
    __shared__ __bf16 wt[192][40];

    const int tid  = threadIdx.x;
    const int wid  = tid >> 6;
    const int lane = tid & 63;
    const int l15  = lane & 15;
    const int l4   = lane >> 4;
    const int m0   = blockIdx.x * 64;

    f32x4 acc[4][3];
    #pragma unroll
    for (int i = 0; i < 4; ++i)
        #pragma unroll
        for (int j = 0; j < 3; ++j)
            acc[i][j] = (f32x4){0.f, 0.f, 0.f, 0.f};

    for (int k0 = 0; k0 < 768; k0 += 32) {
        #pragma unroll
        for (int i = 0; i < 2; ++i) {
            int idx = tid + 256 * i;
            int row = idx >> 3;
            int c4  = idx & 7;
            const float4 v = *reinterpret_cast<const float4*>(
                x + (size_t)(m0 + row) * 768 + k0 + c4 * 4);
            bf16x4 t;
            t[0] = (__bf16)v.x; t[1] = (__bf16)v.y;
            t[2] = (__bf16)v.z; t[3] = (__bf16)v.w;
            *reinterpret_cast<bf16x4*>(&xs[row][c4 * 4]) = t;
        }
        #pragma unroll
        for (int i = 0; i < 6; ++i) {
            int idx = tid + 256 * i;
            int kg  = idx / 192;
            int c   = idx - kg * 192;
            const float* Wm = (c < 64) ? Wq : ((c < 128) ? Wk : Wv);
            int cc = c & 63;
            bf16x4 t;
            #pragma unroll
            for (int j = 0; j < 4; ++j)
                t[j] = (__bf16)Wm[(size_t)(k0 + kg * 4 + j) * 64 + cc];
            *reinterpret_cast<bf16x4*>(&wt[c][kg * 4]) = t;
        }
        __syncthreads();

        bf16x8 afrag[4];
        #pragma unroll
        for (int rf = 0; rf < 4; ++rf)
            afrag[rf] = *reinterpret_cast<const bf16x8*>(&xs[rf * 16 + l15][l4 * 8]);
        #pragma unroll
        for (int cf = 0; cf < 3; ++cf) {
            bf16x8 bfrag = *reinterpret_cast<const bf16x8*>(
                &wt[wid * 48 + cf * 16 + l15][l4 * 8]);
            #pragma unroll
            for (int rf = 0; rf < 4; ++rf)
                acc[rf][cf] = MFMA16(afrag[rf], bfrag, acc[rf][cf]);
        }
        __syncthreads();
    }

    #pragma unroll
    for (int cf = 0; cf < 3; ++cf) {
        int col = wid * 48 + cf * 16 + l15;
        int mi  = col >> 6;                   // 0=Q 1=K 2=V
        int h   = col & 63;
        float bias = (mi == 0) ? bq[h] : ((mi == 1) ? bk[h] : bv[h]);
        float scl  = (mi == 0) ? QSCALE : 1.0f;
        #pragma unroll
        for (int rf = 0; rf < 4; ++rf) {
            int r0 = rf * 16 + l4 * 4;
            if (mi == 2) {
                int m  = m0 + r0;
                int bb = m >> 12;
                int n0 = m & 4095;
                int n0p = (n0 & ~31) | (l4 * 8 + (rf & 1) * 4);
                bf16x4 t;
                #pragma unroll
                for (int r = 0; r < 4; ++r)
                    t[r] = (__bf16)(acc[rf][cf][r] + bias);
                *reinterpret_cast<bf16x4*>(
                    Vpg + ((size_t)bb * 64 + h) * 4096 + n0p) = t;
            } else {
                __bf16* G = (mi == 0) ? Qg : Kg;
                #pragma unroll
                for (int r = 0; r < 4; ++r)
                    G[(size_t)(m0 + r0 + r) * 64 + h] =
                        (__bf16)((acc[rf][cf][r] + bias) * scl);
            }
        }
    }
}

// ---------------------------------------------------------------------------
// Kernel 2: flash attention, barrier-free wave-private loop (r17) + SPLIT
// counted-vmcnt waits (T4, wave-local). Per tile, K's 4 DMAs are issued
// before V's 4; the body waits vmcnt(4) for K only, runs QK+softmax while
// V lands, then vmcnt(4) retires V (with K_{t+1} in flight). Count audit:
//   top of body t:   outstanding {K_t,V_t}=8      -> vmcnt(4) retires K_t
//   after issue K+1: outstanding {V_t,K_{t+1}}=8  -> vmcnt(4) retires V_t
//   after issue V+1: outstanding {K_{t+1},V_{t+1}}=8 (invariant)
// Tail (t=31, no t+1 issue): W2 must be vmcnt(0). sched_barrier(0) after
// each wait (rule #18). Everything else r17-verbatim: block = 4 waves
// (256 thr) = 64 q x 4096 keys, wave-private dbuf K[32][64]/V[64][32]
// (64 KB/block -> 2 blocks/CU), XOR swizzle via pre-swizzled global source,
// no max tracking, raw v_exp_f32, epilogue sequential-overlay merge.
// ---------------------------------------------------------------------------
__global__ __launch_bounds__(256, 2) void attn_kernel(
    const __bf16* __restrict__ Qg, const __bf16* __restrict__ Kg,
    const __bf16* __restrict__ Vpg, float* __restrict__ out)
{
    __shared__ __align__(16) char smem[65536];
    __bf16* ksbase = reinterpret_cast<__bf16*>(smem);
    __bf16* vsbase = ksbase + 4 * 2 * 32 * 64;

    const int tid  = threadIdx.x;
    const int wid  = tid >> 6;
    const int lane = tid & 63;
    const int l15  = lane & 15;
    const int l4   = lane >> 4;
    const int ks   = wid;              // private key stream 0..3
    const int b    = blockIdx.x & 7;   // batch -> XCD
    const int qt   = blockIdx.x >> 3;  // 0..63
    const int q0   = qt * 64;

    const __bf16* Kb = Kg  + (size_t)b * 4096 * 64;
    const __bf16* Vb = Vpg + (size_t)b * 64 * 4096;

    __bf16* kst0 = ksbase + (ks * 2 + 0) * 32 * 64;
    __bf16* kst1 = ksbase + (ks * 2 + 1) * 32 * 64;
    __bf16* vst0 = vsbase + (ks * 2 + 0) * 64 * 32;
    __bf16* vst1 = vsbase + (ks * 2 + 1) * 64 * 32;

    // loop-invariant swizzled LDS element offsets (read side, r9-proven)
    int koff[2][2], voff[4];
    #pragma unroll
    for (int dc = 0; dc < 2; ++dc)
        #pragma unroll
        for (int cf = 0; cf < 2; ++cf) {
            int row = cf * 16 + l15;
            koff[dc][cf] = row * 64 + (((dc * 4 + l4) ^ (row & 7)) * 8);
        }
    #pragma unroll
    for (int ht = 0; ht < 4; ++ht) {
        int row = ht * 16 + l15;
        voff[ht] = row * 32 + ((l4 ^ (row & 3)) * 8);
    }

    // staging source addressing (pre-swizzled global granules, r16-proven)
    const int krow = lane >> 3;                      // 0..7
    const int kg_s = (lane & 7) ^ (lane >> 3);
    const int vrow = lane >> 2;                      // 0..15
    const int vg_s = (lane & 3) ^ ((lane >> 2) & 3);

    auto issue_K = [&](__bf16* kp, int c) {
        #pragma unroll
        for (int j = 0; j < 4; ++j)
            async_copy16(kp + j * 8 * 64,
                         Kb + (size_t)(c * 32 + j * 8 + krow) * 64 + kg_s * 8);
    };
    auto issue_V = [&](__bf16* vp, int c) {
        #pragma unroll
        for (int j = 0; j < 4; ++j)
            async_copy16(vp + j * 16 * 32,
                         Vb + (size_t)(j * 16 + vrow) * 4096 + c * 32 + vg_s * 8);
    };

    // Q B-frags for the four 16-row sets (pre-scaled by QSCALE)
    bf16x8 aq[4][2];
    #pragma unroll
    for (int set = 0; set < 4; ++set)
        #pragma unroll
        for (int dc = 0; dc < 2; ++dc)
            aq[set][dc] = *reinterpret_cast<const bf16x8*>(
                Qg + (size_t)(b * 4096 + q0 + set * 16 + l15) * 64 + dc * 32 + l4 * 8);

    f32x4 lacc[4];
    f32x4 o[4][4];
    #pragma unroll
    for (int set = 0; set < 4; ++set) {
        lacc[set] = (f32x4){0.f, 0.f, 0.f, 0.f};
        #pragma unroll
        for (int ht = 0; ht < 4; ++ht)
            o[set][ht] = (f32x4){0.f, 0.f, 0.f, 0.f};
    }

    const int c0 = ks * 32;            // this wave's first 32-key chunk

    // prologue: Q loads must be consumed before counted waits can be exact;
    // the compiler orders aq's own waitcnt, and prologue DMAs are issued
    // AFTER the aq loads so the counted waits below only see DMA traffic
    // once aq is in registers (first-body vmcnt(4) is conservative anyway:
    // it also retires any remaining aq loads since they are older).
    issue_K(kst0, c0);
    issue_V(vst0, c0);

    for (int t = 0; t < 32; ++t) {
        const __bf16* kp = (t & 1) ? kst1 : kst0;
        const __bf16* vp = (t & 1) ? vst1 : vst0;
        __bf16* kpn = (t & 1) ? kst0 : kst1;
        __bf16* vpn = (t & 1) ? vst0 : vst1;
        const bool pre = (t + 1) < 32;

        // W1: K_t ready (V_t still in flight)
        asm volatile("s_waitcnt vmcnt(4)" ::: "memory");
        __builtin_amdgcn_sched_barrier(0);

        bf16x8 kfr[2][2];
        #pragma unroll
        for (int dc = 0; dc < 2; ++dc)
            #pragma unroll
            for (int cf = 0; cf < 2; ++cf)
                kfr[dc][cf] = *reinterpret_cast<const bf16x8*>(kp + koff[dc][cf]);

        if (pre) issue_K(kpn, c0 + t + 1);

        // S^T = K * Q^T : s[set][cf] reg r = S[q=l15][key = cf*16 + 4*l4 + r]
        f32x4 s[4][2];
        #pragma unroll
        for (int set = 0; set < 4; ++set)
            #pragma unroll
            for (int cf = 0; cf < 2; ++cf)
                s[set][cf] = (f32x4){0.f, 0.f, 0.f, 0.f};
        __builtin_amdgcn_s_setprio(1);
        #pragma unroll
        for (int dc = 0; dc < 2; ++dc)
            #pragma unroll
            for (int cf = 0; cf < 2; ++cf)
                #pragma unroll
                for (int set = 0; set < 4; ++set)
                    s[set][cf] = MFMA16(kfr[dc][cf], aq[set][dc], s[set][cf]);
        __builtin_amdgcn_s_setprio(0);

        // p = 2^s (raw v_exp_f32); accumulate l as vectors
        #pragma unroll
        for (int set = 0; set < 4; ++set) {
            #pragma unroll
            for (int cf = 0; cf < 2; ++cf)
                #pragma unroll
                for (int r = 0; r < 4; ++r)
                    s[set][cf][r] = fast_exp2(s[set][cf][r]);
            lacc[set] += s[set][0];
            lacc[set] += s[set][1];
        }

        // P^T B-frags (in-lane repack, sigma-permuted key order)
        bf16x8 pb[4];
        #pragma unroll
        for (int set = 0; set < 4; ++set)
            #pragma unroll
            for (int j = 0; j < 4; ++j) {
                pb[set][j]     = (__bf16)s[set][0][j];
                pb[set][j + 4] = (__bf16)s[set][1][j];
            }

        // W2: V_t ready (K_{t+1} still in flight); tail drains fully
        if (pre) {
            asm volatile("s_waitcnt vmcnt(4)" ::: "memory");
        } else {
            asm volatile("s_waitcnt vmcnt(0)" ::: "memory");
        }
        __builtin_amdgcn_sched_barrier(0);

        bf16x8 vfr[4];
        #pragma unroll
        for (int ht = 0; ht < 4; ++ht)
            vfr[ht] = *reinterpret_cast<const bf16x8*>(vp + voff[ht]);

        if (pre) issue_V(vpn, c0 + t + 1);

        // O^T += V^T * P^T (each vf feeds 4 sets)
        __builtin_amdgcn_s_setprio(1);
        #pragma unroll
        for (int ht = 0; ht < 4; ++ht)
            #pragma unroll
            for (int set = 0; set < 4; ++set)
                o[set][ht] = MFMA16(vfr[ht], pb[set], o[set][ht]);
        __builtin_amdgcn_s_setprio(0);
    }

    // per-wave l partials (q = set*16 + l15)
    float lw[4];
    #pragma unroll
    for (int set = 0; set < 4; ++set) {
        float v = lacc[set][0] + lacc[set][1] + lacc[set][2] + lacc[set][3];
        v += __shfl_xor(v, 16);
        v += __shfl_xor(v, 32);
        lw[set] = v;
    }

    // ---- sequential-overlay merge of the 4 private streams (plain sums) ----
    __syncthreads();                    // all waves done with the arena
    float* lbuf = reinterpret_cast<float*>(smem);   // [4 ks][64 q]
    float* obuf = lbuf + 256;                       // [64 q][68]
    const int hcol = 4 * l4;

    if (l4 == 0) {
        #pragma unroll
        for (int set = 0; set < 4; ++set)
            lbuf[ks * 64 + set * 16 + l15] = lw[set];
    }
    #pragma unroll
    for (int k = 1; k < 4; ++k) {
        if (ks == k) {
            #pragma unroll
            for (int set = 0; set < 4; ++set)
                #pragma unroll
                for (int ht = 0; ht < 4; ++ht)
                    *reinterpret_cast<f32x4*>(
                        &obuf[(set * 16 + l15) * 68 + ht * 16 + hcol]) = o[set][ht];
        }
        __syncthreads();
        if (ks == 0) {
            #pragma unroll
            for (int set = 0; set < 4; ++set)
                #pragma unroll
                for (int ht = 0; ht < 4; ++ht) {
                    f32x4 p = *reinterpret_cast<const f32x4*>(
                        &obuf[(set * 16 + l15) * 68 + ht * 16 + hcol]);
                    o[set][ht][0] += p[0]; o[set][ht][1] += p[1];
                    o[set][ht][2] += p[2]; o[set][ht][3] += p[3];
                }
        }
        __syncthreads();
    }

    if (ks == 0) {
        #pragma unroll
        for (int set = 0; set < 4; ++set) {
            int q = set * 16 + l15;
            float L = lbuf[q] + lbuf[64 + q] + lbuf[128 + q] + lbuf[192 + q];
            float inv = 1.0f / L;
            #pragma unroll
            for (int ht = 0; ht < 4; ++ht) {
                f32x4 acc = o[set][ht];
                acc[0] *= inv; acc[1] *= inv; acc[2] *= inv; acc[3] *= inv;
                *reinterpret_cast<f32x4*>(
                    out + (size_t)(b * 4096 + q0 + q) * 64 + ht * 16 + hcol) = acc;
            }
        }
    }
}

extern "C" void kernel_launch(void* const* d_in, const int* in_sizes, int n_in,
                              void* d_out, int out_size, void* d_ws, size_t ws_size,
                              hipStream_t stream)
{
    (void)in_sizes; (void)n_in; (void)out_size; (void)ws_size;
    const float* x  = (const float*)d_in[0];
    const float* Wq = (const float*)d_in[1];
    const float* bq = (const float*)d_in[2];
    const float* Wk = (const float*)d_in[3];
    const float* bk = (const float*)d_in[4];
    const float* Wv = (const float*)d_in[5];
    const float* bv = (const float*)d_in[6];
    float* out = (float*)d_out;

    __bf16* Qg  = (__bf16*)d_ws;                    // [32768][64] bf16 (scaled)
    __bf16* Kg  = Qg + (size_t)32768 * 64;          // [32768][64] bf16
    __bf16* Vpg = Kg + (size_t)32768 * 64;          // [8][64][4096] bf16 permuted

    qkv_proj_kernel<<<512, 256, 0, stream>>>(x, Wq, bq, Wk, bk, Wv, bv, Qg, Kg, Vpg);
    attn_kernel<<<512, 256, 0, stream>>>(Qg, Kg, Vpg, out);
}

// Round 19
// 71.259 us; speedup vs baseline: 1.1662x; 1.0246x over previous
//
#include <hip/hip_runtime.h>
#include <stdint.h>
#include <stddef.h>

typedef __bf16 bf16x8 __attribute__((ext_vector_type(8)));
typedef __bf16 bf16x4 __attribute__((ext_vector_type(4)));
typedef float  f32x4  __attribute__((ext_vector_type(4)));

#define MFMA16(A, B, C) __builtin_amdgcn_mfma_f32_16x16x32_bf16((A), (B), (C), 0, 0, 0)

// 0.125 (1/sqrt(64)) * log2(e), folded into Q at projection time.
#define QSCALE 0.18033688011112042f

// Raw v_exp_f32 (2^x); args bounded here so no range guards needed.
#if __has_builtin(__builtin_amdgcn_exp2f)
__device__ __forceinline__ float fast_exp2(float x) {
    return __builtin_amdgcn_exp2f(x);
}
#else
__device__ __forceinline__ float fast_exp2(float x) {
    float r;
    asm("v_exp_f32 %0, %1" : "=v"(r) : "v"(x));
    return r;
}
#endif

// Async global->LDS, 16B per lane. LDS dest is wave-uniform base + lane*16.
__device__ __forceinline__ void async_copy16(__bf16* lds, const __bf16* g) {
    __builtin_amdgcn_global_load_lds(
        (const __attribute__((address_space(1))) void*)g,
        (__attribute__((address_space(3))) void*)lds,
        16, 0, 0);
}

// ---------------------------------------------------------------------------
// Kernel 1: fused QKV projection.
//   x [32768][768] fp32 -> Q (pre-scaled by QSCALE), K bf16 row-major
//   [32768][64]; V stored CHUNK-MAJOR: Vc[b][128 chunks][64 h][32 k'] with
//   (a) the sigma key-permutation inside each 32-token chunk:
//       token (16*hi + 4*g + r) -> k' position (8*g + 4*hi + r), and
//   (b) the LDS stage swizzle baked in: the bf16x4 destined for (h, granule
//       gt) is stored at granule gt^(h&3) -> attention DMA is fully linear
//       (1024 contiguous bytes per instruction, same as K).
// ---------------------------------------------------------------------------
__global__ __launch_bounds__(256) void qkv_proj_kernel(
    const float* __restrict__ x,
    const float* __restrict__ Wq, const float* __restrict__ bq,
    const float* __restrict__ Wk, const float* __restrict__ bk,
    const float* __restrict__ Wv, const float* __restrict__ bv,
    __bf16* __restrict__ Qg, __bf16* __restrict__ Kg, __bf16* __restrict__ Vcg)
{
    __shared__ __bf16 xs[64][40];
    __shared__ __bf16 wt[192][40];

    const int tid  = threadIdx.x;
    const int wid  = tid >> 6;
    const int lane = tid & 63;
    const int l15  = lane & 15;
    const int l4   = lane >> 4;
    const int m0   = blockIdx.x * 64;

    f32x4 acc[4][3];
    #pragma unroll
    for (int i = 0; i < 4; ++i)
        #pragma unroll
        for (int j = 0; j < 3; ++j)
            acc[i][j] = (f32x4){0.f, 0.f, 0.f, 0.f};

    for (int k0 = 0; k0 < 768; k0 += 32) {
        #pragma unroll
        for (int i = 0; i < 2; ++i) {
            int idx = tid + 256 * i;
            int row = idx >> 3;
            int c4  = idx & 7;
            const float4 v = *reinterpret_cast<const float4*>(
                x + (size_t)(m0 + row) * 768 + k0 + c4 * 4);
            bf16x4 t;
            t[0] = (__bf16)v.x; t[1] = (__bf16)v.y;
            t[2] = (__bf16)v.z; t[3] = (__bf16)v.w;
            *reinterpret_cast<bf16x4*>(&xs[row][c4 * 4]) = t;
        }
        #pragma unroll
        for (int i = 0; i < 6; ++i) {
            int idx = tid + 256 * i;
            int kg  = idx / 192;
            int c   = idx - kg * 192;
            const float* Wm = (c < 64) ? Wq : ((c < 128) ? Wk : Wv);
            int cc = c & 63;
            bf16x4 t;
            #pragma unroll
            for (int j = 0; j < 4; ++j)
                t[j] = (__bf16)Wm[(size_t)(k0 + kg * 4 + j) * 64 + cc];
            *reinterpret_cast<bf16x4*>(&wt[c][kg * 4]) = t;
        }
        __syncthreads();

        bf16x8 afrag[4];
        #pragma unroll
        for (int rf = 0; rf < 4; ++rf)
            afrag[rf] = *reinterpret_cast<const bf16x8*>(&xs[rf * 16 + l15][l4 * 8]);
        #pragma unroll
        for (int cf = 0; cf < 3; ++cf) {
            bf16x8 bfrag = *reinterpret_cast<const bf16x8*>(
                &wt[wid * 48 + cf * 16 + l15][l4 * 8]);
            #pragma unroll
            for (int rf = 0; rf < 4; ++rf)
                acc[rf][cf] = MFMA16(afrag[rf], bfrag, acc[rf][cf]);
        }
        __syncthreads();
    }

    #pragma unroll
    for (int cf = 0; cf < 3; ++cf) {
        int col = wid * 48 + cf * 16 + l15;
        int mi  = col >> 6;                   // 0=Q 1=K 2=V
        int h   = col & 63;
        float bias = (mi == 0) ? bq[h] : ((mi == 1) ? bk[h] : bv[h]);
        float scl  = (mi == 0) ? QSCALE : 1.0f;
        #pragma unroll
        for (int rf = 0; rf < 4; ++rf) {
            int r0 = rf * 16 + l4 * 4;
            if (mi == 2) {
                int m  = m0 + r0;
                int bb = m >> 12;
                int n0 = m & 4095;
                int c  = n0 >> 5;                         // key chunk
                // sigma pos: granule gt = l4, half = rf&1; bake swizzle:
                int goff = ((l4 ^ (h & 3)) * 8) + (rf & 1) * 4;
                bf16x4 t;
                #pragma unroll
                for (int r = 0; r < 4; ++r)
                    t[r] = (__bf16)(acc[rf][cf][r] + bias);
                *reinterpret_cast<bf16x4*>(
                    Vcg + (((size_t)bb * 128 + c) * 64 + h) * 32 + goff) = t;
            } else {
                __bf16* G = (mi == 0) ? Qg : Kg;
                #pragma unroll
                for (int r = 0; r < 4; ++r)
                    G[(size_t)(m0 + r0 + r) * 64 + h] =
                        (__bf16)((acc[rf][cf][r] + bias) * scl);
            }
        }
    }
}

// ---------------------------------------------------------------------------
// Kernel 2: flash attention — r18 VERBATIM (barrier-free wave-private loop,
// split counted-vmcnt K/V waits) except the V staging source: chunk-major
// Vc layout makes each V DMA instruction read 1024 CONTIGUOUS bytes (was a
// 16-row x 64B scatter at 8KB stride). LDS image is bit-identical to r18
// (swizzle baked into the stored layout; read offsets unchanged).
// ---------------------------------------------------------------------------
__global__ __launch_bounds__(256, 2) void attn_kernel(
    const __bf16* __restrict__ Qg, const __bf16* __restrict__ Kg,
    const __bf16* __restrict__ Vcg, float* __restrict__ out)
{
    __shared__ __align__(16) char smem[65536];
    __bf16* ksbase = reinterpret_cast<__bf16*>(smem);
    __bf16* vsbase = ksbase + 4 * 2 * 32 * 64;

    const int tid  = threadIdx.x;
    const int wid  = tid >> 6;
    const int lane = tid & 63;
    const int l15  = lane & 15;
    const int l4   = lane >> 4;
    const int ks   = wid;              // private key stream 0..3
    const int b    = blockIdx.x & 7;   // batch -> XCD
    const int qt   = blockIdx.x >> 3;  // 0..63
    const int q0   = qt * 64;

    const __bf16* Kb = Kg  + (size_t)b * 4096 * 64;
    const __bf16* Vb = Vcg + (size_t)b * 128 * 2048;   // [128 chunks][64][32]

    __bf16* kst0 = ksbase + (ks * 2 + 0) * 32 * 64;
    __bf16* kst1 = ksbase + (ks * 2 + 1) * 32 * 64;
    __bf16* vst0 = vsbase + (ks * 2 + 0) * 64 * 32;
    __bf16* vst1 = vsbase + (ks * 2 + 1) * 64 * 32;

    // loop-invariant swizzled LDS element offsets (read side, unchanged)
    int koff[2][2], voff[4];
    #pragma unroll
    for (int dc = 0; dc < 2; ++dc)
        #pragma unroll
        for (int cf = 0; cf < 2; ++cf) {
            int row = cf * 16 + l15;
            koff[dc][cf] = row * 64 + (((dc * 4 + l4) ^ (row & 7)) * 8);
        }
    #pragma unroll
    for (int ht = 0; ht < 4; ++ht) {
        int row = ht * 16 + l15;
        voff[ht] = row * 32 + ((l4 ^ (row & 3)) * 8);
    }

    // staging source addressing: K pre-swizzled (r9-proven); V now LINEAR.
    const int krow = lane >> 3;                      // 0..7
    const int kg_s = (lane & 7) ^ (lane >> 3);
    const int vlin = lane * 16;                      // lane*16 elems (32B... 16 elems)

    auto issue_K = [&](__bf16* kp, int c) {
        #pragma unroll
        for (int j = 0; j < 4; ++j)
            async_copy16(kp + j * 8 * 64,
                         Kb + (size_t)(c * 32 + j * 8 + krow) * 64 + kg_s * 8);
    };
    auto issue_V = [&](__bf16* vp, int c) {
        const __bf16* src = Vb + (size_t)c * 2048;   // contiguous 4 KB tile
        #pragma unroll
        for (int j = 0; j < 4; ++j)
            async_copy16(vp + j * 512, src + j * 512 + (lane & 63) * 8);
    };

    // Q B-frags for the four 16-row sets (pre-scaled by QSCALE)
    bf16x8 aq[4][2];
    #pragma unroll
    for (int set = 0; set < 4; ++set)
        #pragma unroll
        for (int dc = 0; dc < 2; ++dc)
            aq[set][dc] = *reinterpret_cast<const bf16x8*>(
                Qg + (size_t)(b * 4096 + q0 + set * 16 + l15) * 64 + dc * 32 + l4 * 8);

    f32x4 lacc[4];
    f32x4 o[4][4];
    #pragma unroll
    for (int set = 0; set < 4; ++set) {
        lacc[set] = (f32x4){0.f, 0.f, 0.f, 0.f};
        #pragma unroll
        for (int ht = 0; ht < 4; ++ht)
            o[set][ht] = (f32x4){0.f, 0.f, 0.f, 0.f};
    }

    const int c0 = ks * 32;            // this wave's first 32-key chunk
    issue_K(kst0, c0);
    issue_V(vst0, c0);

    for (int t = 0; t < 32; ++t) {
        const __bf16* kp = (t & 1) ? kst1 : kst0;
        const __bf16* vp = (t & 1) ? vst1 : vst0;
        __bf16* kpn = (t & 1) ? kst0 : kst1;
        __bf16* vpn = (t & 1) ? vst0 : vst1;
        const bool pre = (t + 1) < 32;

        // W1: K_t ready (V_t still in flight)
        asm volatile("s_waitcnt vmcnt(4)" ::: "memory");
        __builtin_amdgcn_sched_barrier(0);

        bf16x8 kfr[2][2];
        #pragma unroll
        for (int dc = 0; dc < 2; ++dc)
            #pragma unroll
            for (int cf = 0; cf < 2; ++cf)
                kfr[dc][cf] = *reinterpret_cast<const bf16x8*>(kp + koff[dc][cf]);

        if (pre) issue_K(kpn, c0 + t + 1);

        // S^T = K * Q^T
        f32x4 s[4][2];
        #pragma unroll
        for (int set = 0; set < 4; ++set)
            #pragma unroll
            for (int cf = 0; cf < 2; ++cf)
                s[set][cf] = (f32x4){0.f, 0.f, 0.f, 0.f};
        __builtin_amdgcn_s_setprio(1);
        #pragma unroll
        for (int dc = 0; dc < 2; ++dc)
            #pragma unroll
            for (int cf = 0; cf < 2; ++cf)
                #pragma unroll
                for (int set = 0; set < 4; ++set)
                    s[set][cf] = MFMA16(kfr[dc][cf], aq[set][dc], s[set][cf]);
        __builtin_amdgcn_s_setprio(0);

        // p = 2^s; accumulate l as vectors
        #pragma unroll
        for (int set = 0; set < 4; ++set) {
            #pragma unroll
            for (int cf = 0; cf < 2; ++cf)
                #pragma unroll
                for (int r = 0; r < 4; ++r)
                    s[set][cf][r] = fast_exp2(s[set][cf][r]);
            lacc[set] += s[set][0];
            lacc[set] += s[set][1];
        }

        // P^T B-frags (in-lane repack, sigma-permuted key order)
        bf16x8 pb[4];
        #pragma unroll
        for (int set = 0; set < 4; ++set)
            #pragma unroll
            for (int j = 0; j < 4; ++j) {
                pb[set][j]     = (__bf16)s[set][0][j];
                pb[set][j + 4] = (__bf16)s[set][1][j];
            }

        // W2: V_t ready (K_{t+1} in flight); tail drains fully
        if (pre) {
            asm volatile("s_waitcnt vmcnt(4)" ::: "memory");
        } else {
            asm volatile("s_waitcnt vmcnt(0)" ::: "memory");
        }
        __builtin_amdgcn_sched_barrier(0);

        bf16x8 vfr[4];
        #pragma unroll
        for (int ht = 0; ht < 4; ++ht)
            vfr[ht] = *reinterpret_cast<const bf16x8*>(vp + voff[ht]);

        if (pre) issue_V(vpn, c0 + t + 1);

        // O^T += V^T * P^T
        __builtin_amdgcn_s_setprio(1);
        #pragma unroll
        for (int ht = 0; ht < 4; ++ht)
            #pragma unroll
            for (int set = 0; set < 4; ++set)
                o[set][ht] = MFMA16(vfr[ht], pb[set], o[set][ht]);
        __builtin_amdgcn_s_setprio(0);
    }

    // per-wave l partials (q = set*16 + l15)
    float lw[4];
    #pragma unroll
    for (int set = 0; set < 4; ++set) {
        float v = lacc[set][0] + lacc[set][1] + lacc[set][2] + lacc[set][3];
        v += __shfl_xor(v, 16);
        v += __shfl_xor(v, 32);
        lw[set] = v;
    }

    // ---- sequential-overlay merge of the 4 private streams (plain sums) ----
    __syncthreads();
    float* lbuf = reinterpret_cast<float*>(smem);   // [4 ks][64 q]
    float* obuf = lbuf + 256;                       // [64 q][68]
    const int hcol = 4 * l4;

    if (l4 == 0) {
        #pragma unroll
        for (int set = 0; set < 4; ++set)
            lbuf[ks * 64 + set * 16 + l15] = lw[set];
    }
    #pragma unroll
    for (int k = 1; k < 4; ++k) {
        if (ks == k) {
            #pragma unroll
            for (int set = 0; set < 4; ++set)
                #pragma unroll
                for (int ht = 0; ht < 4; ++ht)
                    *reinterpret_cast<f32x4*>(
                        &obuf[(set * 16 + l15) * 68 + ht * 16 + hcol]) = o[set][ht];
        }
        __syncthreads();
        if (ks == 0) {
            #pragma unroll
            for (int set = 0; set < 4; ++set)
                #pragma unroll
                for (int ht = 0; ht < 4; ++ht) {
                    f32x4 p = *reinterpret_cast<const f32x4*>(
                        &obuf[(set * 16 + l15) * 68 + ht * 16 + hcol]);
                    o[set][ht][0] += p[0]; o[set][ht][1] += p[1];
                    o[set][ht][2] += p[2]; o[set][ht][3] += p[3];
                }
        }
        __syncthreads();
    }

    if (ks == 0) {
        #pragma unroll
        for (int set = 0; set < 4; ++set) {
            int q = set * 16 + l15;
            float L = lbuf[q] + lbuf[64 + q] + lbuf[128 + q] + lbuf[192 + q];
            float inv = 1.0f / L;
            #pragma unroll
            for (int ht = 0; ht < 4; ++ht) {
                f32x4 acc = o[set][ht];
                acc[0] *= inv; acc[1] *= inv; acc[2] *= inv; acc[3] *= inv;
                *reinterpret_cast<f32x4*>(
                    out + (size_t)(b * 4096 + q0 + q) * 64 + ht * 16 + hcol) = acc;
            }
        }
    }
}

extern "C" void kernel_launch(void* const* d_in, const int* in_sizes, int n_in,
                              void* d_out, int out_size, void* d_ws, size_t ws_size,
                              hipStream_t stream)
{
    (void)in_sizes; (void)n_in; (void)out_size; (void)ws_size;
    const float* x  = (const float*)d_in[0];
    const float* Wq = (const float*)d_in[1];
    const float* bq = (const float*)d_in[2];
    const float* Wk = (const float*)d_in[3];
    const float* bk = (const float*)d_in[4];
    const float* Wv = (const float*)d_in[5];
    const float* bv = (const float*)d_in[6];
    float* out = (float*)d_out;

    __bf16* Qg  = (__bf16*)d_ws;                    // [32768][64] bf16 (scaled)
    __bf16* Kg  = Qg + (size_t)32768 * 64;          // [32768][64] bf16
    __bf16* Vcg = Kg + (size_t)32768 * 64;          // [8][128][64][32] bf16

    qkv_proj_kernel<<<512, 256, 0, stream>>>(x, Wq, bq, Wk, bk, Wv, bv, Qg, Kg, Vcg);
    attn_kernel<<<512, 256, 0, stream>>>(Qg, Kg, Vcg, out);
}